// Round 5
// baseline (49.411 us; speedup 1.0000x reference)
//
#include <hip/hip_runtime.h>

// YOLO loss (forward only), fused single kernel.
// pred: [N,7,7,20] f32 -> 80 B/cell (16B-aligned). tgt: [N,7,7,6] f32 -> 24 B/cell.
// Output: scalar f32 = total / N.
//
// R5: 4 cells/thread (32 outstanding loads/thread -> 4x MLP per wave),
// 784 blocks x 256 threads covers 802816 cells exactly. Cross-block reduce
// fused via threadfence + atomic ticket; last block sums 784 f64 partials
// in fixed order (deterministic) and writes out. No second kernel launch.

#define SBLK 256
#define CPT  4                 // cells per thread
#define CPB  (SBLK * CPT)      // 1024 cells per block

constexpr float L_COORD = 5.0f;
constexpr float L_NOOBJ = 0.5f;
constexpr float EPS_    = 1e-6f;

__device__ __forceinline__ float clamp01(float x) { return fminf(fmaxf(x, 0.0f), 1.0f); }

__device__ __forceinline__ float iou_f(float l1l, float l1t, float w1, float h1,
                                       float l2l, float l2t, float w2, float h2) {
    float l1r = l1l + w1, l1b = l1t + h1;
    float l2r = l2l + w2, l2b = l2t + h2;
    float a1 = w1 * h1, a2 = w2 * h2;
    bool cont_by2 = (l2l <= l1l) && (l2t <= l1t) && (l2r >= l1r) && (l2b >= l1b);
    bool cont_by1 = (l1l <= l2l) && (l1t <= l2t) && (l1r >= l2r) && (l1b >= l2b);
    bool sep = (l1r <= l2l) || (l2r <= l1l) || (l1b <= l2t) || (l2b <= l1t);
    float iw = fminf(l1r, l2r) - fmaxf(l1l, l2l);
    float ih = fminf(l1b, l2b) - fmaxf(l1t, l2t);
    float inter = iw * ih;
    float gen = inter * __builtin_amdgcn_rcpf(a1 + a2 - inter);
    float r = sep ? 0.0f : gen;
    r = cont_by1 ? a2 * __builtin_amdgcn_rcpf(a1) : r;
    r = cont_by2 ? a1 * __builtin_amdgcn_rcpf(a2) : r;   // outermost where wins
    return r;
}

__device__ __forceinline__ float cell_loss(float4 pa, float4 pb, float4 pc,
                                           float4 pd, float4 pe,
                                           float2 t0, float2 t1, float2 tc) {
    float conf = tc.x;
    float coo = (conf > 0.0f) ? 1.0f : 0.0f;
    float noo = (conf == 0.0f) ? 1.0f : 0.0f;

    float d0 = pb.x - conf, d1 = pc.y - conf;
    float noobj = noo * (d0 * d0 + d1 * d1);

    float b0l = pa.x, b0t = pa.y, b0w = pa.z, b0h = pa.w, b0c = pb.x;
    float b1l = pb.y, b1t = pb.z, b1w = pb.w, b1h = pc.x, b1c = pc.y;
    float btl = t0.x, btt = t0.y, btw = t1.x, bth = t1.y;

    float iou0 = iou_f(b0l, b0t, b0w, b0h, btl, btt, btw, bth);
    float iou1 = iou_f(b1l, b1t, b1w, b1h, btl, btt, btw, bth);
    bool pick0 = (iou0 >= iou1);
    float max_iou = pick0 ? iou0 : iou1;

    float rl = pick0 ? b0l : b1l;
    float rt = pick0 ? b0t : b1t;
    float rw = pick0 ? b0w : b1w;
    float rh = pick0 ? b0h : b1h;
    float rc = pick0 ? b0c : b1c;
    float nc = pick0 ? b1c : b0c;

    float cd = rc - max_iou;
    float contain = cd * cd;
    float not_contain = nc * nc;

    float ex = clamp01(rl) - clamp01(btl);
    float ey = clamp01(rt) - clamp01(btt);
    float sw = __builtin_amdgcn_sqrtf(fminf(fmaxf(rw, EPS_), 1.0f))
             - __builtin_amdgcn_sqrtf(fminf(fmaxf(btw, EPS_), 1.0f));
    float sh = __builtin_amdgcn_sqrtf(fminf(fmaxf(rh, EPS_), 1.0f))
             - __builtin_amdgcn_sqrtf(fminf(fmaxf(bth, EPS_), 1.0f));
    float loc = ex * ex + ey * ey + sw * sw + sh * sh;

    float lg0 = pc.z, lg1 = pc.w;
    float lg2 = pd.x, lg3 = pd.y, lg4 = pd.z, lg5 = pd.w;
    float lg6 = pe.x, lg7 = pe.y, lg8 = pe.z, lg9 = pe.w;
    float m = fmaxf(lg0, lg1);
    m = fmaxf(m, fmaxf(lg2, lg3));
    m = fmaxf(m, fmaxf(lg4, lg5));
    m = fmaxf(m, fmaxf(lg6, lg7));
    m = fmaxf(m, fmaxf(lg8, lg9));
    float ssum = __expf(lg0 - m) + __expf(lg1 - m) + __expf(lg2 - m) +
                 __expf(lg3 - m) + __expf(lg4 - m) + __expf(lg5 - m) +
                 __expf(lg6 - m) + __expf(lg7 - m) + __expf(lg8 - m) +
                 __expf(lg9 - m);
    float logz = m + __logf(ssum);
    int ci = (int)tc.y;
    float picked = lg0;
    picked = (ci == 1) ? lg1 : picked;
    picked = (ci == 2) ? lg2 : picked;
    picked = (ci == 3) ? lg3 : picked;
    picked = (ci == 4) ? lg4 : picked;
    picked = (ci == 5) ? lg5 : picked;
    picked = (ci == 6) ? lg6 : picked;
    picked = (ci == 7) ? lg7 : picked;
    picked = (ci == 8) ? lg8 : picked;
    picked = (ci == 9) ? lg9 : picked;
    float cls_loss = logz - picked;

    return L_COORD * (coo * loc)
         + 2.0f * (coo * contain)
         + (coo * not_contain)
         + L_NOOBJ * noobj
         + coo * cls_loss;
}

__global__ __launch_bounds__(SBLK) void yolo_loss_fused(
        const float* __restrict__ pred, const float* __restrict__ tgt,
        double* __restrict__ partials, unsigned* __restrict__ ticket,
        float* __restrict__ out, int ncells, double invN) {
    __shared__ float smw[SBLK / 64];
    __shared__ double smd[SBLK / 64];
    __shared__ int last_flag;

    int block0 = blockIdx.x * CPB;
    int nblocks = gridDim.x;

    // ---- issue ALL loads upfront: 32 outstanding per thread ----
    float4 pa[CPT], pb[CPT], pc[CPT], pd[CPT], pe[CPT];
    float2 t0[CPT], t1[CPT], tc[CPT];
    #pragma unroll
    for (int k = 0; k < CPT; ++k) {
        int ik = block0 + k * SBLK + threadIdx.x;
        if (ik < ncells) {
            const float4* p4 = reinterpret_cast<const float4*>(pred + (size_t)ik * 20);
            pa[k] = p4[0]; pb[k] = p4[1]; pc[k] = p4[2]; pd[k] = p4[3]; pe[k] = p4[4];
            const float2* t2 = reinterpret_cast<const float2*>(tgt + (size_t)ik * 6);
            t0[k] = t2[0]; t1[k] = t2[1]; tc[k] = t2[2];
        } else {
            pa[k] = pb[k] = pc[k] = pd[k] = pe[k] = make_float4(0.f, 0.f, 0.f, 0.f);
            t0[k] = t1[k] = make_float2(0.f, 0.f);
            tc[k] = make_float2(-1.0f, 0.f);   // conf=-1 -> coo=0, noo=0
        }
    }

    float total = 0.0f;
    #pragma unroll
    for (int k = 0; k < CPT; ++k)
        total += cell_loss(pa[k], pb[k], pc[k], pd[k], pe[k], t0[k], t1[k], tc[k]);

    // ---- block reduce: f32 wave shuffle -> LDS -> f64 partial ----
    float v = total;
    #pragma unroll
    for (int off = 32; off > 0; off >>= 1)
        v += __shfl_down(v, off, 64);
    int lane = threadIdx.x & 63;
    int wid  = threadIdx.x >> 6;
    if (lane == 0) smw[wid] = v;
    __syncthreads();
    if (threadIdx.x == 0) {
        double s = 0.0;
        #pragma unroll
        for (int w = 0; w < SBLK / 64; ++w) s += (double)smw[w];
        partials[blockIdx.x] = s;
        __threadfence();                        // release partial device-wide
        unsigned prev = atomicAdd(ticket, 1u);  // device-scope
        last_flag = (prev == (unsigned)(nblocks - 1)) ? 1 : 0;
    }
    __syncthreads();

    // ---- last-arriving block: final reduce of nblocks f64 partials ----
    if (last_flag) {
        __threadfence();                        // acquire
        double s = 0.0;
        for (int idx = threadIdx.x; idx < nblocks; idx += SBLK)
            s += __hip_atomic_load(&partials[idx], __ATOMIC_RELAXED,
                                   __HIP_MEMORY_SCOPE_AGENT);
        #pragma unroll
        for (int off = 32; off > 0; off >>= 1)
            s += __shfl_down(s, off, 64);
        if (lane == 0) smd[wid] = s;
        __syncthreads();
        if (threadIdx.x == 0) {
            double t = 0.0;
            #pragma unroll
            for (int w = 0; w < SBLK / 64; ++w) t += smd[w];
            out[0] = (float)(t * invN);
        }
    }
}

extern "C" void kernel_launch(void* const* d_in, const int* in_sizes, int n_in,
                              void* d_out, int out_size, void* d_ws, size_t ws_size,
                              hipStream_t stream) {
    const float* pred = (const float*)d_in[0];
    const float* tgt  = (const float*)d_in[1];
    int ncells = in_sizes[0] / 20;          // N*7*7 = 802816
    int N = ncells / 49;

    int nblocks = (ncells + CPB - 1) / CPB; // 784 for the bench shape
    double* partials = (double*)d_ws;
    unsigned* ticket = (unsigned*)((char*)d_ws + (size_t)nblocks * sizeof(double));

    hipMemsetAsync(ticket, 0, sizeof(unsigned), stream);
    yolo_loss_fused<<<nblocks, SBLK, 0, stream>>>(pred, tgt, partials, ticket,
                                                  (float*)d_out, ncells,
                                                  1.0 / (double)N);
}

// Round 6
// 26.264 us; speedup vs baseline: 1.8813x; 1.8813x over previous
//
#include <hip/hip_runtime.h>

// YOLO loss (forward only). One thread per (n, s, s) cell.
// pred: [N,7,7,20] f32 -> 80 B/cell (16B-aligned). tgt: [N,7,7,6] f32 -> 24 B/cell.
// Output: scalar f32 = total / N.
//
// R6 = R2 structure (1 cell/thread, direct loads: proven best) with the tail
// replaced: per-block f64 atomicAdd into 64 SPREAD buckets (blockIdx & 63,
// each on its own cache line -> ~49 serialized RMWs per bucket, no
// single-address storm like R1) + a single-wave reduce kernel over 64 f64.
// Keeps R4's numerically-safe VALU cuts (v_rcp, v_sqrt, f32 wave reduce).

#define SBLK 256
#define NBUCKET 64

constexpr float L_COORD = 5.0f;
constexpr float L_NOOBJ = 0.5f;
constexpr float EPS_    = 1e-6f;

__device__ __forceinline__ float clamp01(float x) { return fminf(fmaxf(x, 0.0f), 1.0f); }

__device__ __forceinline__ float iou_f(float l1l, float l1t, float w1, float h1,
                                       float l2l, float l2t, float w2, float h2) {
    float l1r = l1l + w1, l1b = l1t + h1;
    float l2r = l2l + w2, l2b = l2t + h2;
    float a1 = w1 * h1, a2 = w2 * h2;
    bool cont_by2 = (l2l <= l1l) && (l2t <= l1t) && (l2r >= l1r) && (l2b >= l1b);
    bool cont_by1 = (l1l <= l2l) && (l1t <= l2t) && (l1r >= l2r) && (l1b >= l2b);
    bool sep = (l1r <= l2l) || (l2r <= l1l) || (l1b <= l2t) || (l2b <= l1t);
    float iw = fminf(l1r, l2r) - fmaxf(l1l, l2l);
    float ih = fminf(l1b, l2b) - fmaxf(l1t, l2t);
    float inter = iw * ih;
    float gen = inter * __builtin_amdgcn_rcpf(a1 + a2 - inter);
    float r = sep ? 0.0f : gen;
    r = cont_by1 ? a2 * __builtin_amdgcn_rcpf(a1) : r;
    r = cont_by2 ? a1 * __builtin_amdgcn_rcpf(a2) : r;   // outermost where wins
    return r;
}

__global__ __launch_bounds__(SBLK) void yolo_loss_kernel(
        const float* __restrict__ pred, const float* __restrict__ tgt,
        double* __restrict__ buckets, int ncells) {
    int i = blockIdx.x * SBLK + threadIdx.x;
    float total = 0.0f;
    if (i < ncells) {
        const float4* p4 = reinterpret_cast<const float4*>(pred + (size_t)i * 20);
        float4 pa = p4[0];  // pred[0..3]
        float4 pb = p4[1];  // pred[4..7]
        float4 pc = p4[2];  // pred[8..11]
        float4 pd = p4[3];  // pred[12..15]
        float4 pe = p4[4];  // pred[16..19]
        const float2* t2 = reinterpret_cast<const float2*>(tgt + (size_t)i * 6);
        float2 t0 = t2[0];  // (left, top)
        float2 t1 = t2[1];  // (w, h)
        float2 tc = t2[2];  // (conf, cls)

        float conf = tc.x;
        float coo = (conf > 0.0f) ? 1.0f : 0.0f;
        float noo = (conf == 0.0f) ? 1.0f : 0.0f;

        float d0 = pb.x - conf, d1 = pc.y - conf;
        float noobj = noo * (d0 * d0 + d1 * d1);

        float b0l = pa.x, b0t = pa.y, b0w = pa.z, b0h = pa.w, b0c = pb.x;
        float b1l = pb.y, b1t = pb.z, b1w = pb.w, b1h = pc.x, b1c = pc.y;
        float btl = t0.x, btt = t0.y, btw = t1.x, bth = t1.y;

        float iou0 = iou_f(b0l, b0t, b0w, b0h, btl, btt, btw, bth);
        float iou1 = iou_f(b1l, b1t, b1w, b1h, btl, btt, btw, bth);
        bool pick0 = (iou0 >= iou1);
        float max_iou = pick0 ? iou0 : iou1;

        float rl = pick0 ? b0l : b1l;
        float rt = pick0 ? b0t : b1t;
        float rw = pick0 ? b0w : b1w;
        float rh = pick0 ? b0h : b1h;
        float rc = pick0 ? b0c : b1c;
        float nc = pick0 ? b1c : b0c;

        float cd = rc - max_iou;
        float contain = cd * cd;
        float not_contain = nc * nc;

        float ex = clamp01(rl) - clamp01(btl);
        float ey = clamp01(rt) - clamp01(btt);
        float sw = __builtin_amdgcn_sqrtf(fminf(fmaxf(rw, EPS_), 1.0f))
                 - __builtin_amdgcn_sqrtf(fminf(fmaxf(btw, EPS_), 1.0f));
        float sh = __builtin_amdgcn_sqrtf(fminf(fmaxf(rh, EPS_), 1.0f))
                 - __builtin_amdgcn_sqrtf(fminf(fmaxf(bth, EPS_), 1.0f));
        float loc = ex * ex + ey * ey + sw * sw + sh * sh;

        float lg0 = pc.z, lg1 = pc.w;
        float lg2 = pd.x, lg3 = pd.y, lg4 = pd.z, lg5 = pd.w;
        float lg6 = pe.x, lg7 = pe.y, lg8 = pe.z, lg9 = pe.w;
        float m = fmaxf(lg0, lg1);
        m = fmaxf(m, fmaxf(lg2, lg3));
        m = fmaxf(m, fmaxf(lg4, lg5));
        m = fmaxf(m, fmaxf(lg6, lg7));
        m = fmaxf(m, fmaxf(lg8, lg9));
        float ssum = __expf(lg0 - m) + __expf(lg1 - m) + __expf(lg2 - m) +
                     __expf(lg3 - m) + __expf(lg4 - m) + __expf(lg5 - m) +
                     __expf(lg6 - m) + __expf(lg7 - m) + __expf(lg8 - m) +
                     __expf(lg9 - m);
        float logz = m + __logf(ssum);
        int ci = (int)tc.y;
        float picked = lg0;
        picked = (ci == 1) ? lg1 : picked;
        picked = (ci == 2) ? lg2 : picked;
        picked = (ci == 3) ? lg3 : picked;
        picked = (ci == 4) ? lg4 : picked;
        picked = (ci == 5) ? lg5 : picked;
        picked = (ci == 6) ? lg6 : picked;
        picked = (ci == 7) ? lg7 : picked;
        picked = (ci == 8) ? lg8 : picked;
        picked = (ci == 9) ? lg9 : picked;
        float cls_loss = logz - picked;

        total = L_COORD * (coo * loc)
              + 2.0f * (coo * contain)
              + (coo * not_contain)
              + L_NOOBJ * noobj
              + coo * cls_loss;
    }

    // block reduce: f32 wave shuffle -> LDS -> one f64 atomic into a spread bucket
    float v = total;
    #pragma unroll
    for (int off = 32; off > 0; off >>= 1)
        v += __shfl_down(v, off, 64);
    __shared__ float smw[SBLK / 64];
    int lane = threadIdx.x & 63;
    int wid  = threadIdx.x >> 6;
    if (lane == 0) smw[wid] = v;
    __syncthreads();
    if (threadIdx.x == 0) {
        double s = 0.0;
        #pragma unroll
        for (int w = 0; w < SBLK / 64; ++w) s += (double)smw[w];
        atomicAdd(&buckets[blockIdx.x & (NBUCKET - 1)], s);
    }
}

__global__ __launch_bounds__(64) void yolo_reduce_kernel(
        const double* __restrict__ buckets, float* __restrict__ out, double invN) {
    double v = buckets[threadIdx.x];
    #pragma unroll
    for (int off = 32; off > 0; off >>= 1)
        v += __shfl_down(v, off, 64);
    if (threadIdx.x == 0)
        out[0] = (float)(v * invN);
}

extern "C" void kernel_launch(void* const* d_in, const int* in_sizes, int n_in,
                              void* d_out, int out_size, void* d_ws, size_t ws_size,
                              hipStream_t stream) {
    const float* pred = (const float*)d_in[0];
    const float* tgt  = (const float*)d_in[1];
    int ncells = in_sizes[0] / 20;          // N*7*7 = 802816
    int N = ncells / 49;

    double* buckets = (double*)d_ws;
    hipMemsetAsync(buckets, 0, NBUCKET * sizeof(double), stream);
    int nblocks = (ncells + SBLK - 1) / SBLK;
    yolo_loss_kernel<<<nblocks, SBLK, 0, stream>>>(pred, tgt, buckets, ncells);
    yolo_reduce_kernel<<<1, 64, 0, stream>>>(buckets, (float*)d_out, 1.0 / (double)N);
}

// Round 7
// 21.877 us; speedup vs baseline: 2.2586x; 1.2005x over previous
//
#include <hip/hip_runtime.h>

// YOLO loss (forward only). One thread per (n, s, s) cell.
// pred: [N,7,7,20] f32 -> 80 B/cell (16B-aligned). tgt: [N,7,7,6] f32 -> 24 B/cell.
// Output: scalar f32 = total / N.
//
// R7 = R2/R4 body with SBLK 256 -> 1024. R1 profile showed the 2nd launch
// costs <1us; the main kernel is ~20us at 50% occupancy (4-wave blocks cap
// at 4 blocks/CU = 16 waves). 16-wave blocks at 2 blocks/CU = 32 waves/CU
// = 100% occupancy -> double the latency hiding. Grid = 784 = 802816/1024
// exactly. No atomics, no memset, f64 partials + tiny reduce kernel.

#define SBLK 1024

constexpr float L_COORD = 5.0f;
constexpr float L_NOOBJ = 0.5f;
constexpr float EPS_    = 1e-6f;

__device__ __forceinline__ float clamp01(float x) { return fminf(fmaxf(x, 0.0f), 1.0f); }

__device__ __forceinline__ float iou_f(float l1l, float l1t, float w1, float h1,
                                       float l2l, float l2t, float w2, float h2) {
    float l1r = l1l + w1, l1b = l1t + h1;
    float l2r = l2l + w2, l2b = l2t + h2;
    float a1 = w1 * h1, a2 = w2 * h2;
    bool cont_by2 = (l2l <= l1l) && (l2t <= l1t) && (l2r >= l1r) && (l2b >= l1b);
    bool cont_by1 = (l1l <= l2l) && (l1t <= l2t) && (l1r >= l2r) && (l1b >= l2b);
    bool sep = (l1r <= l2l) || (l2r <= l1l) || (l1b <= l2t) || (l2b <= l1t);
    float iw = fminf(l1r, l2r) - fmaxf(l1l, l2l);
    float ih = fminf(l1b, l2b) - fmaxf(l1t, l2t);
    float inter = iw * ih;
    float gen = inter * __builtin_amdgcn_rcpf(a1 + a2 - inter);
    float r = sep ? 0.0f : gen;
    r = cont_by1 ? a2 * __builtin_amdgcn_rcpf(a1) : r;
    r = cont_by2 ? a1 * __builtin_amdgcn_rcpf(a2) : r;   // outermost where wins
    return r;
}

__global__ __launch_bounds__(SBLK) void yolo_loss_kernel(
        const float* __restrict__ pred, const float* __restrict__ tgt,
        double* __restrict__ partials, int ncells) {
    int i = blockIdx.x * SBLK + threadIdx.x;
    float total = 0.0f;
    if (i < ncells) {
        const float4* p4 = reinterpret_cast<const float4*>(pred + (size_t)i * 20);
        float4 pa = p4[0];  // pred[0..3]
        float4 pb = p4[1];  // pred[4..7]
        float4 pc = p4[2];  // pred[8..11]
        float4 pd = p4[3];  // pred[12..15]
        float4 pe = p4[4];  // pred[16..19]
        const float2* t2 = reinterpret_cast<const float2*>(tgt + (size_t)i * 6);
        float2 t0 = t2[0];  // (left, top)
        float2 t1 = t2[1];  // (w, h)
        float2 tc = t2[2];  // (conf, cls)

        float conf = tc.x;
        float coo = (conf > 0.0f) ? 1.0f : 0.0f;
        float noo = (conf == 0.0f) ? 1.0f : 0.0f;

        float d0 = pb.x - conf, d1 = pc.y - conf;
        float noobj = noo * (d0 * d0 + d1 * d1);

        float b0l = pa.x, b0t = pa.y, b0w = pa.z, b0h = pa.w, b0c = pb.x;
        float b1l = pb.y, b1t = pb.z, b1w = pb.w, b1h = pc.x, b1c = pc.y;
        float btl = t0.x, btt = t0.y, btw = t1.x, bth = t1.y;

        float iou0 = iou_f(b0l, b0t, b0w, b0h, btl, btt, btw, bth);
        float iou1 = iou_f(b1l, b1t, b1w, b1h, btl, btt, btw, bth);
        bool pick0 = (iou0 >= iou1);
        float max_iou = pick0 ? iou0 : iou1;

        float rl = pick0 ? b0l : b1l;
        float rt = pick0 ? b0t : b1t;
        float rw = pick0 ? b0w : b1w;
        float rh = pick0 ? b0h : b1h;
        float rc = pick0 ? b0c : b1c;
        float nc = pick0 ? b1c : b0c;

        float cd = rc - max_iou;
        float contain = cd * cd;
        float not_contain = nc * nc;

        float ex = clamp01(rl) - clamp01(btl);
        float ey = clamp01(rt) - clamp01(btt);
        float sw = __builtin_amdgcn_sqrtf(fminf(fmaxf(rw, EPS_), 1.0f))
                 - __builtin_amdgcn_sqrtf(fminf(fmaxf(btw, EPS_), 1.0f));
        float sh = __builtin_amdgcn_sqrtf(fminf(fmaxf(rh, EPS_), 1.0f))
                 - __builtin_amdgcn_sqrtf(fminf(fmaxf(bth, EPS_), 1.0f));
        float loc = ex * ex + ey * ey + sw * sw + sh * sh;

        float lg0 = pc.z, lg1 = pc.w;
        float lg2 = pd.x, lg3 = pd.y, lg4 = pd.z, lg5 = pd.w;
        float lg6 = pe.x, lg7 = pe.y, lg8 = pe.z, lg9 = pe.w;
        float m = fmaxf(lg0, lg1);
        m = fmaxf(m, fmaxf(lg2, lg3));
        m = fmaxf(m, fmaxf(lg4, lg5));
        m = fmaxf(m, fmaxf(lg6, lg7));
        m = fmaxf(m, fmaxf(lg8, lg9));
        float ssum = __expf(lg0 - m) + __expf(lg1 - m) + __expf(lg2 - m) +
                     __expf(lg3 - m) + __expf(lg4 - m) + __expf(lg5 - m) +
                     __expf(lg6 - m) + __expf(lg7 - m) + __expf(lg8 - m) +
                     __expf(lg9 - m);
        float logz = m + __logf(ssum);
        int ci = (int)tc.y;
        float picked = lg0;
        picked = (ci == 1) ? lg1 : picked;
        picked = (ci == 2) ? lg2 : picked;
        picked = (ci == 3) ? lg3 : picked;
        picked = (ci == 4) ? lg4 : picked;
        picked = (ci == 5) ? lg5 : picked;
        picked = (ci == 6) ? lg6 : picked;
        picked = (ci == 7) ? lg7 : picked;
        picked = (ci == 8) ? lg8 : picked;
        picked = (ci == 9) ? lg9 : picked;
        float cls_loss = logz - picked;

        total = L_COORD * (coo * loc)
              + 2.0f * (coo * contain)
              + (coo * not_contain)
              + L_NOOBJ * noobj
              + coo * cls_loss;
    }

    // block reduce: f32 wave shuffle -> LDS -> one f64 store per block
    float v = total;
    #pragma unroll
    for (int off = 32; off > 0; off >>= 1)
        v += __shfl_down(v, off, 64);
    __shared__ float smw[SBLK / 64];
    int lane = threadIdx.x & 63;
    int wid  = threadIdx.x >> 6;
    if (lane == 0) smw[wid] = v;
    __syncthreads();
    if (threadIdx.x == 0) {
        double s = 0.0;
        #pragma unroll
        for (int w = 0; w < SBLK / 64; ++w) s += (double)smw[w];
        partials[blockIdx.x] = s;   // no atomic: unique slot per block
    }
}

#define RBLK 1024

__global__ __launch_bounds__(RBLK) void yolo_reduce_kernel(
        const double* __restrict__ partials, int nparts,
        float* __restrict__ out, double invN) {
    double v = 0.0;
    for (int idx = threadIdx.x; idx < nparts; idx += RBLK)
        v += partials[idx];
    #pragma unroll
    for (int off = 32; off > 0; off >>= 1)
        v += __shfl_down(v, off, 64);
    __shared__ double sm[RBLK / 64];
    int lane = threadIdx.x & 63;
    int wid  = threadIdx.x >> 6;
    if (lane == 0) sm[wid] = v;
    __syncthreads();
    if (threadIdx.x == 0) {
        double s = 0.0;
        #pragma unroll
        for (int w = 0; w < RBLK / 64; ++w) s += sm[w];
        out[0] = (float)(s * invN);
    }
}

extern "C" void kernel_launch(void* const* d_in, const int* in_sizes, int n_in,
                              void* d_out, int out_size, void* d_ws, size_t ws_size,
                              hipStream_t stream) {
    const float* pred = (const float*)d_in[0];
    const float* tgt  = (const float*)d_in[1];
    int ncells = in_sizes[0] / 20;          // N*7*7 = 802816
    int N = ncells / 49;

    int nblocks = (ncells + SBLK - 1) / SBLK;   // 784 for the bench shape
    yolo_loss_kernel<<<nblocks, SBLK, 0, stream>>>(pred, tgt, (double*)d_ws, ncells);
    yolo_reduce_kernel<<<1, RBLK, 0, stream>>>((const double*)d_ws, nblocks,
                                               (float*)d_out, 1.0 / (double)N);
}